// Round 11
// baseline (116.577 us; speedup 1.0000x reference)
//
#include <hip/hip_runtime.h>
#include <hip/hip_fp16.h>
#include <math.h>
#include <stdint.h>

#define IN_DIM  256
#define OUT_DIM 256
#define NROWS   68     // G + K
#define NT      71     // knot count
#define BATCH   512
#define W_ELEMS (NROWS * IN_DIM * OUT_DIM)   // 4,456,448
#define PART_FLOATS (8 * BATCH * OUT_DIM)    // 1,048,576 floats = 4 MB
#define WB_U32S (W_ELEMS / 2)                // f16-pair words

// ---- Kernel A: convert w fp32 -> packed f16 pairs (f16 > bf16 precision,
//      and enables v_fma_mix_f32 consume). Block 0 zeroes bgroup flags. ----
__global__ __launch_bounds__(256) void cvt_kernel(const float* __restrict__ w,
                                                  uint32_t* __restrict__ wb,
                                                  int* __restrict__ flags) {
  if (blockIdx.x == 0 && threadIdx.x < 64) flags[threadIdx.x] = 0;
  const int base = (blockIdx.x * 256 + threadIdx.x) * 8;   // 8 floats / thread
  const float4 a = *(const float4*)(w + base);
  const float4 b = *(const float4*)(w + base + 4);
  uint4 o;
  o.x = (uint32_t)__half_as_ushort(__float2half_rn(a.x)) |
        ((uint32_t)__half_as_ushort(__float2half_rn(a.y)) << 16);
  o.y = (uint32_t)__half_as_ushort(__float2half_rn(a.z)) |
        ((uint32_t)__half_as_ushort(__float2half_rn(a.w)) << 16);
  o.z = (uint32_t)__half_as_ushort(__float2half_rn(b.x)) |
        ((uint32_t)__half_as_ushort(__float2half_rn(b.y)) << 16);
  o.w = (uint32_t)__half_as_ushort(__float2half_rn(b.z)) |
        ((uint32_t)__half_as_ushort(__float2half_rn(b.w)) << 16);
  *(uint4*)(wb + base / 2) = o;
}

// ---- Kernel B: R7's proven gather (8 b x 32 c, grid 512, batch-issue,
//      static cchunk = bid&7) with two local changes:
//      (1) f16 weights consumed via half2float -> v_fma_mix_f32 (1 VALU/elem
//          instead of extract+fma = 2);
//      (2) final cross-chunk reduction FUSED: 8th-arriving block per bgroup
//          (device-scope ticket) sums the 8 partial slices into out. ----
__device__ __forceinline__ void fma8(const uint4 q, const float y, float* acc) {
  const __half2 h0 = __builtin_bit_cast(__half2, q.x);
  const __half2 h1 = __builtin_bit_cast(__half2, q.y);
  const __half2 h2 = __builtin_bit_cast(__half2, q.z);
  const __half2 h3 = __builtin_bit_cast(__half2, q.w);
  acc[0] += y * __half2float(h0.x);
  acc[1] += y * __half2float(h0.y);
  acc[2] += y * __half2float(h1.x);
  acc[3] += y * __half2float(h1.y);
  acc[4] += y * __half2float(h2.x);
  acc[5] += y * __half2float(h2.y);
  acc[6] += y * __half2float(h3.x);
  acc[7] += y * __half2float(h3.y);
}

__global__ __launch_bounds__(256) void kan_gather_kernel(
    const float* __restrict__ x, const uint4* __restrict__ wp,
    const float* __restrict__ t, float* __restrict__ part,
    int* __restrict__ flags, float* __restrict__ out) {
  __shared__ float  lt[NT];
  __shared__ float4 nA[32][8];    // N0..N3 per (local c, local b)
  __shared__ float  sA[32][8];    // silu(x)
  __shared__ int    bA[32][8];    // base row (i-3)
  __shared__ float  red[4][2048]; // per-wave partials: [wave][b*256 + o]
  __shared__ int    s_old;

  const int tid = threadIdx.x;
  const unsigned bid = blockIdx.x;
  // cchunk = bid&7 -> XCD affinity heuristic (free; affinity twice shown ~0
  // but harmless). bgroup = 8 batch rows.
  const int cchunk = bid & 7;
  const int bgroup = bid >> 3;   // 64 groups of 8 batch rows

  if (tid < NT) lt[tid] = t[tid];
  __syncthreads();

  // ---- Phase 1: basis for 8 b x 32 c; exactly one (b,c) pair per thread ----
  {
    const int bb = tid >> 5;
    const int cl = tid & 31;
    const float xv = x[(size_t)(bgroup * 8 + bb) * IN_DIM + cchunk * 32 + cl];
    int i = 3 + (int)floorf((xv + 1.0f) * 32.0f);
    i = i < 3 ? 3 : (i > 66 ? 66 : i);
    while (i > 3 && xv < lt[i]) --i;
    while (i < 66 && xv >= lt[i + 1]) ++i;

    float N0 = 1.f, N1 = 0.f, N2 = 0.f, N3 = 0.f;
    { // p = 1
      const float l1 = xv - lt[i];
      const float r1 = lt[i + 1] - xv;
      const float tp = N0 / (r1 + l1);
      N1 = l1 * tp; N0 = r1 * tp;
    }
    { // p = 2
      const float l1 = xv - lt[i];
      const float l2 = xv - lt[i - 1];
      const float r1 = lt[i + 1] - xv;
      const float r2 = lt[i + 2] - xv;
      float saved = 0.f;
      const float tp0 = N0 / (r1 + l2);
      const float n0 = saved + r1 * tp0; saved = l2 * tp0;
      const float tp1 = N1 / (r2 + l1);
      const float n1 = saved + r2 * tp1; saved = l1 * tp1;
      N0 = n0; N1 = n1; N2 = saved;
    }
    { // p = 3
      const float l1 = xv - lt[i];
      const float l2 = xv - lt[i - 1];
      const float l3 = xv - lt[i - 2];
      const float r1 = lt[i + 1] - xv;
      const float r2 = lt[i + 2] - xv;
      const float r3 = lt[i + 3] - xv;
      float saved = 0.f;
      const float tp0 = N0 / (r1 + l3);
      const float n0 = saved + r1 * tp0; saved = l3 * tp0;
      const float tp1 = N1 / (r2 + l2);
      const float n1 = saved + r2 * tp1; saved = l2 * tp1;
      const float tp2 = N2 / (r3 + l1);
      const float n2 = saved + r3 * tp2; saved = l1 * tp2;
      N0 = n0; N1 = n1; N2 = n2; N3 = saved;
    }
    nA[cl][bb] = make_float4(N0, N1, N2, N3);
    sA[cl][bb] = xv / (1.0f + expf(-xv));
    bA[cl][bb] = i - 3;
  }
  __syncthreads();

  // ---- Phase 2: wave = 2 channels/pass (half-wave each, 32 lanes x uint4 =
  //      full 256-o f16 row), 4 passes. Batch-issue 33 loads, then FMAs. ----
  const int wv   = tid >> 6;
  const int lane = tid & 63;
  const int half = lane >> 5;
  const int ol   = lane & 31;     // uint4 (8-o) slot: o = ol*8 + j

  float acc[8][8];
  #pragma unroll
  for (int b = 0; b < 8; ++b) {
    #pragma unroll
    for (int j = 0; j < 8; ++j) acc[b][j] = 0.f;
  }

  for (int pp = 0; pp < 4; ++pp) {
    const int cl = wv * 8 + pp * 2 + half;            // local c, 0..31
    const uint32_t cbase = (uint32_t)((cchunk * 32 + cl) * 32 + ol);
    const uint4 q4 = wp[cbase + 67u * 8192u];         // silu row

    uint4 q[8][4];
    #pragma unroll
    for (int b = 0; b < 8; ++b) {
      const uint32_t rb = cbase + ((uint32_t)bA[cl][b] << 13);
      q[b][0] = wp[rb];
      q[b][1] = wp[rb +  8192u];
      q[b][2] = wp[rb + 16384u];
      q[b][3] = wp[rb + 24576u];
    }
    #pragma unroll
    for (int b = 0; b < 8; ++b) {
      const float4 yv = nA[cl][b];
      const float  ys = sA[cl][b];
      fma8(q[b][0], yv.x, acc[b]);
      fma8(q[b][1], yv.y, acc[b]);
      fma8(q[b][2], yv.z, acc[b]);
      fma8(q[b][3], yv.w, acc[b]);
      fma8(q4,      ys,   acc[b]);
    }
  }

  // fold the two half-waves (partner lane holds the pass's other channel)
  #pragma unroll
  for (int b = 0; b < 8; ++b) {
    #pragma unroll
    for (int j = 0; j < 8; ++j)
      acc[b][j] += __shfl_xor(acc[b][j], 32, 64);
  }

  if (half == 0) {
    #pragma unroll
    for (int b = 0; b < 8; ++b) {
      #pragma unroll
      for (int j = 0; j < 8; ++j)
        red[wv][b * 256 + ol * 8 + j] = acc[b][j];
    }
  }
  __syncthreads();

  // ---- Phase 3: sum the 4 waves, store this c-chunk's partial ----
  const int b  = tid >> 5;         // local batch row
  const int oo = tid & 31;         // 8-float slot
  {
    float s[8] = {0.f, 0.f, 0.f, 0.f, 0.f, 0.f, 0.f, 0.f};
    #pragma unroll
    for (int w2 = 0; w2 < 4; ++w2) {
      const float* rr = &red[w2][b * 256 + oo * 8];
      #pragma unroll
      for (int j = 0; j < 8; ++j) s[j] += rr[j];
    }
    float* dst = part + ((size_t)cchunk * BATCH + bgroup * 8 + b) * OUT_DIM + oo * 8;
    *(float4*)dst       = make_float4(s[0], s[1], s[2], s[3]);
    *(float4*)(dst + 4) = make_float4(s[4], s[5], s[6], s[7]);
  }

  // ---- Phase 4: fused cross-chunk reduction. __syncthreads drains all the
  //      block's stores (vmcnt0 before s_barrier); ticket via device-scope
  //      atomic; 8th arriver sums the 8 slices for its bgroup. ----
  __syncthreads();
  if (tid == 0) {
    __threadfence();                         // release: partials -> device
    s_old = atomicAdd(&flags[bgroup], 1);    // device-scope ticket
  }
  __syncthreads();
  if (s_old == 7) {
    if (tid == 0) __threadfence();           // acquire: invalidate stale lines
    __syncthreads();
    const float* pb = part + ((size_t)bgroup * 8 + b) * OUT_DIM + oo * 8;
    const int S = BATCH * OUT_DIM;
    float4 lo[8], hi[8];
    #pragma unroll
    for (int k = 0; k < 8; ++k) {            // batch-issue all 16 loads
      lo[k] = *(const float4*)(pb + (size_t)k * S);
      hi[k] = *(const float4*)(pb + (size_t)k * S + 4);
    }
    float4 s0 = lo[0], s1 = hi[0];
    #pragma unroll
    for (int k = 1; k < 8; ++k) {
      s0.x += lo[k].x; s0.y += lo[k].y; s0.z += lo[k].z; s0.w += lo[k].w;
      s1.x += hi[k].x; s1.y += hi[k].y; s1.z += hi[k].z; s1.w += hi[k].w;
    }
    float* d = out + ((size_t)bgroup * 8 + b) * OUT_DIM + oo * 8;
    *(float4*)d       = s0;
    *(float4*)(d + 4) = s1;
  }
}

extern "C" void kernel_launch(void* const* d_in, const int* in_sizes, int n_in,
                              void* d_out, int out_size, void* d_ws, size_t ws_size,
                              hipStream_t stream) {
  const float* x = (const float*)d_in[0];
  const float* w = (const float*)d_in[1];
  const float* t = (const float*)d_in[2];
  float* out  = (float*)d_out;
  float* part = (float*)d_ws;                          // 4 MB of partials
  uint32_t* wb = (uint32_t*)d_ws + PART_FLOATS;        // f16 weights
  int* flags = (int*)(wb + WB_U32S);                   // 64 bgroup tickets
  cvt_kernel<<<W_ELEMS / (256 * 8), 256, 0, stream>>>(w, wb, flags);
  kan_gather_kernel<<<512, 256, 0, stream>>>(x, (const uint4*)wb, t, part, flags, out);
}

// Round 12
// 100.117 us; speedup vs baseline: 1.1644x; 1.1644x over previous
//
#include <hip/hip_runtime.h>
#include <hip/hip_fp16.h>
#include <math.h>
#include <stdint.h>

#define IN_DIM  256
#define OUT_DIM 256
#define NROWS   68     // G + K
#define NT      71     // knot count
#define BATCH   512
#define KPAD    96     // 68 rows padded to 3 x K32 MFMA blocks
#define NCG     32     // 32 cgroups x 8 channels
#define PART_FLOATS (NCG * BATCH * OUT_DIM)          // 4,194,304 floats = 16 MB
#define WB_SHORTS   (IN_DIM * OUT_DIM * KPAD)        // 6,291,456 f16 = 12.6 MB

typedef _Float16 f16x8 __attribute__((ext_vector_type(8)));
typedef float    f32x4 __attribute__((ext_vector_type(4)));

// ---- Kernel A: w[k][c][o] fp32 -> wb[c][o][k(96, zero-padded)] f16.
//      LDS-bounced transpose per (c, 64-o tile); both reads and writes
//      coalesced. One-time cost so the gather's MFMA operands are
//      k-contiguous (every CDNA frag holds 8 consecutive k per lane). ----
__global__ __launch_bounds__(256) void cvt_kernel(const float* __restrict__ w,
                                                  unsigned short* __restrict__ wb) {
  __shared__ unsigned short l16[NROWS][64];
  const int c  = blockIdx.x >> 2;
  const int ot = (blockIdx.x & 3) << 6;
  const int t  = threadIdx.x;
  const int o1 = t & 63, k0 = t >> 6;
  for (int k = k0; k < NROWS; k += 4) {
    const float v = w[((size_t)k * IN_DIM + c) * OUT_DIM + ot + o1];
    l16[k][o1] = __half_as_ushort(__float2half_rn(v));
  }
  __syncthreads();
  // 64 o-rows x 96 k = 768 uint4; 3 per thread
  #pragma unroll
  for (int i = 0; i < 3; ++i) {
    const int u = t + 256 * i;
    const int o2 = u / 12, seg = u % 12, k8 = seg * 8;
    uint32_t hl[4];
    #pragma unroll
    for (int j = 0; j < 4; ++j) {
      const int ka = k8 + 2 * j, kb = ka + 1;
      const uint32_t lo = (ka < NROWS) ? l16[ka][o2] : 0u;
      const uint32_t hi = (kb < NROWS) ? l16[kb][o2] : 0u;
      hl[j] = lo | (hi << 16);
    }
    *(uint4*)(wb + ((size_t)(c * 256 + ot + o2) * KPAD + k8)) =
        make_uint4(hl[0], hl[1], hl[2], hl[3]);
  }
}

// ---- Kernel B: MFMA gather. Block = 64 b x 8 ch (grid 256 = 8 btile x 32 cg,
//      1 block/CU). Per ch: Y[64][96] f16 built in LDS (5 nonzeros/row),
//      W-tile [256 o][96 k] f16 staged 48 KB via global_load_lds (dbuf;
//      barrier placed AFTER next-stage issue so compute covers its latency),
//      192 x mfma_f32_16x16x32_f16: A = W^T (lane: o=l&15, k=(l>>4)*8+e),
//      B = Y^T (lane: b=l&15, same k), D[o][b] (col=lane&15=b,
//      row=(lane>>4)*4+reg=o -- m89-verified C/D map). ----
__global__ __launch_bounds__(256) void kan_gather_kernel(
    const float* __restrict__ x, const unsigned short* __restrict__ wbu,
    const float* __restrict__ t, float* __restrict__ part) {
  __shared__ uint4 Wb[2][3072];                 // 2 x 48 KB W tiles
  __shared__ unsigned short Ylds[64 * 104];     // [b][k] pitch 104 (13.3 KB)
  __shared__ float4 nA[8][64];
  __shared__ float  sA[8][64];
  __shared__ int    bA[8][64];
  __shared__ float  lt[NT];

  const int tid   = threadIdx.x;
  const int cg    = blockIdx.x & 31;
  const int btile = blockIdx.x >> 5;
  const int wv    = tid >> 6;
  const int lane  = tid & 63;
  const int m16   = lane & 15;
  const int g16b  = (lane >> 4) * 16;           // k-group byte offset

  if (tid < NT) lt[tid] = t[tid];
  __syncthreads();                               // lt visible

  // issue stage(ch=0) -> Wb[0]; latency covered by basis phase
  {
    const char* src0 = (const char*)wbu + (size_t)(cg * 8 + 0) * 49152;
    #pragma unroll
    for (int j = 0; j < 12; ++j) {
      const int s = wv * 12 + j;
      __builtin_amdgcn_global_load_lds((const uint32_t*)(src0 + s * 1024 + lane * 16),
                                       (uint32_t*)(&Wb[0][s * 64]), 16, 0, 0);
    }
  }

  // ---- Phase 1: basis for 64 b x 8 c (proven code) ----
  for (int p = tid; p < 512; p += 256) {
    const int c = p >> 6, bb = p & 63;
    const float xv = x[(size_t)(btile * 64 + bb) * IN_DIM + cg * 8 + c];
    int i = 3 + (int)floorf((xv + 1.0f) * 32.0f);
    i = i < 3 ? 3 : (i > 66 ? 66 : i);
    while (i > 3 && xv < lt[i]) --i;
    while (i < 66 && xv >= lt[i + 1]) ++i;
    float N0 = 1.f, N1 = 0.f, N2 = 0.f, N3 = 0.f;
    { const float l1 = xv - lt[i], r1 = lt[i + 1] - xv;
      const float tp = N0 / (r1 + l1); N1 = l1 * tp; N0 = r1 * tp; }
    { const float l1 = xv - lt[i], l2 = xv - lt[i - 1];
      const float r1 = lt[i + 1] - xv, r2 = lt[i + 2] - xv;
      float saved = 0.f;
      const float tp0 = N0 / (r1 + l2); const float n0 = saved + r1 * tp0; saved = l2 * tp0;
      const float tp1 = N1 / (r2 + l1); const float n1 = saved + r2 * tp1; saved = l1 * tp1;
      N0 = n0; N1 = n1; N2 = saved; }
    { const float l1 = xv - lt[i], l2 = xv - lt[i - 1], l3 = xv - lt[i - 2];
      const float r1 = lt[i + 1] - xv, r2 = lt[i + 2] - xv, r3 = lt[i + 3] - xv;
      float saved = 0.f;
      const float tp0 = N0 / (r1 + l3); const float n0 = saved + r1 * tp0; saved = l3 * tp0;
      const float tp1 = N1 / (r2 + l2); const float n1 = saved + r2 * tp1; saved = l2 * tp1;
      const float tp2 = N2 / (r3 + l1); const float n2 = saved + r3 * tp2; saved = l1 * tp2;
      N0 = n0; N1 = n1; N2 = n2; N3 = saved; }
    nA[c][bb] = make_float4(N0, N1, N2, N3);
    sA[c][bb] = xv / (1.0f + expf(-xv));
    bA[c][bb] = i - 3;
  }
  __syncthreads();   // basis visible; stage(0) drained (vmcnt0 at barrier)

  f32x4 acc[4][4];
  #pragma unroll
  for (int a = 0; a < 4; ++a)
    #pragma unroll
    for (int b = 0; b < 4; ++b) acc[a][b] = f32x4{0.f, 0.f, 0.f, 0.f};

  for (int ch = 0; ch < 8; ++ch) {
    // ---- Y-build: zero [64][104], scatter 5 f16 per b-row ----
    for (int i = tid; i < 1664; i += 256)
      *(uint2*)((char*)Ylds + (size_t)i * 8) = make_uint2(0u, 0u);
    __syncthreads();               // zeros visible before scatter (cross-wave rows)
    if (tid < 64) {
      const int bb = tid;
      unsigned short* yr = &Ylds[bb * 104];
      const float4 yv = nA[ch][bb];
      const int base = bA[ch][bb];
      yr[base + 0] = __half_as_ushort(__float2half_rn(yv.x));
      yr[base + 1] = __half_as_ushort(__float2half_rn(yv.y));
      yr[base + 2] = __half_as_ushort(__float2half_rn(yv.z));
      yr[base + 3] = __half_as_ushort(__float2half_rn(yv.w));
      yr[67]       = __half_as_ushort(__float2half_rn(sA[ch][bb]));
    }
    __syncthreads();               // (B): Y ready; nothing in flight

    // issue stage(ch+1): latency covered by compute(ch); drained at (A)
    if (ch < 7) {
      const char* srcN = (const char*)wbu + (size_t)(cg * 8 + ch + 1) * 49152;
      uint4* dstN = &Wb[(ch + 1) & 1][0];
      #pragma unroll
      for (int j = 0; j < 12; ++j) {
        const int s = wv * 12 + j;
        __builtin_amdgcn_global_load_lds((const uint32_t*)(srcN + s * 1024 + lane * 16),
                                         (uint32_t*)(dstN + s * 64), 16, 0, 0);
      }
    }

    // ---- compute(ch): 48 MFMA/wave on Wb[ch&1] ----
    const char* Wc = (const char*)&Wb[ch & 1][0];
    #pragma unroll
    for (int kb = 0; kb < 3; ++kb) {
      f16x8 af[4];
      #pragma unroll
      for (int ot = 0; ot < 4; ++ot) {
        const int o = wv * 64 + ot * 16 + m16;
        af[ot] = *(const f16x8*)(Wc + o * 192 + kb * 64 + g16b);
      }
      #pragma unroll
      for (int bt = 0; bt < 4; ++bt) {
        const f16x8 bf = *(const f16x8*)((const char*)Ylds + (bt * 16 + m16) * 208 + kb * 64 + g16b);
        #pragma unroll
        for (int ot = 0; ot < 4; ++ot)
          acc[ot][bt] = __builtin_amdgcn_mfma_f32_16x16x32_f16(af[ot], bf, acc[ot][bt], 0, 0, 0);
      }
    }
    __syncthreads();               // (A): compute done; drains stage(ch+1)
  }

  // ---- Epilogue: acc -> padded LDS bounce -> coalesced partial store ----
  float* bounce = (float*)&Wb[0][0];             // 64 x 260 f32 (66.5 KB)
  #pragma unroll
  for (int ot = 0; ot < 4; ++ot)
    #pragma unroll
    for (int bt = 0; bt < 4; ++bt)
      #pragma unroll
      for (int r = 0; r < 4; ++r) {
        const int o = wv * 64 + ot * 16 + (lane >> 4) * 4 + r;
        const int b = bt * 16 + m16;
        bounce[b * 260 + o] = acc[ot][bt][r];
      }
  __syncthreads();
  #pragma unroll
  for (int i = 0; i < 16; ++i) {
    const int idx = tid + 256 * i;
    const int b = idx >> 6, o4 = (idx & 63) * 4;
    const float4 v = *(const float4*)&bounce[b * 260 + o4];
    *(float4*)(part + ((size_t)cg * BATCH + btile * 64 + b) * OUT_DIM + o4) = v;
  }
}

// ---- Kernel C: reduce the 32 c-group partials into out ----
__global__ __launch_bounds__(256) void reduce_kernel(const float* __restrict__ part,
                                                     float* __restrict__ out) {
  const int q = blockIdx.x * 256 + threadIdx.x;   // float4 index, 32768 total
  const int S = BATCH * OUT_DIM / 4;
  const float4* p = (const float4*)part;
  float4 s = p[q];
  #pragma unroll
  for (int k = 1; k < NCG; ++k) {
    const float4 a = p[q + k * S];
    s.x += a.x; s.y += a.y; s.z += a.z; s.w += a.w;
  }
  ((float4*)out)[q] = s;
}

extern "C" void kernel_launch(void* const* d_in, const int* in_sizes, int n_in,
                              void* d_out, int out_size, void* d_ws, size_t ws_size,
                              hipStream_t stream) {
  const float* x = (const float*)d_in[0];
  const float* w = (const float*)d_in[1];
  const float* t = (const float*)d_in[2];
  float* out  = (float*)d_out;
  float* part = (float*)d_ws;                                   // 16 MB partials
  unsigned short* wb = (unsigned short*)((float*)d_ws + PART_FLOATS);  // f16 W^T
  cvt_kernel<<<1024, 256, 0, stream>>>(w, wb);
  kan_gather_kernel<<<256, 256, 0, stream>>>(x, wb, t, part);
  reduce_kernel<<<BATCH * OUT_DIM / 4 / 256, 256, 0, stream>>>(part, out);
}

// Round 13
// 96.987 us; speedup vs baseline: 1.2020x; 1.0323x over previous
//
#include <hip/hip_runtime.h>
#include <hip/hip_fp16.h>
#include <math.h>
#include <stdint.h>

#define IN_DIM  256
#define OUT_DIM 256
#define NROWS   68     // G + K
#define NT      71     // knot count
#define BATCH   512
#define KPAD    96     // 68 rows -> 3 x K32 MFMA blocks
#define NCG     32     // 32 cgroups x 8 channels
#define PART_FLOATS (NCG * BATCH * OUT_DIM)       // 16 MB of partials
#define WB_SHORTS   (IN_DIM * OUT_DIM * KPAD)     // 6,291,456 f16 = 12.6 MB

typedef _Float16 f16x8 __attribute__((ext_vector_type(8)));
typedef float    f32x4 __attribute__((ext_vector_type(4)));

// ---- Kernel A: w[k][c][o] fp32 -> wb[c][kb][o][32k] f16 (zero-pad k>=68).
//      One block per channel c. Stage 1: coalesced 1 KB row reads -> LDS
//      (pitch 264 so stage-2 column reads spread banks). Stage 2: pack
//      uint4s; consecutive threads write contiguous 1 KB. This layout makes
//      each gather A-frag wave-load one CONTIGUOUS 1 KB block. ----
__global__ __launch_bounds__(256) void cvt_kernel(const float* __restrict__ w,
                                                  unsigned short* __restrict__ wb) {
  __shared__ unsigned short l16[NROWS][264];
  const int c = blockIdx.x;
  const int t = threadIdx.x;
  const int o4 = (t & 63) * 4;
  for (int k = (t >> 6); k < NROWS; k += 4) {
    const float4 v = *(const float4*)(w + ((size_t)k * IN_DIM + c) * OUT_DIM + o4);
    l16[k][o4 + 0] = __half_as_ushort(__float2half_rn(v.x));
    l16[k][o4 + 1] = __half_as_ushort(__float2half_rn(v.y));
    l16[k][o4 + 2] = __half_as_ushort(__float2half_rn(v.z));
    l16[k][o4 + 3] = __half_as_ushort(__float2half_rn(v.w));
  }
  __syncthreads();
  #pragma unroll
  for (int i = 0; i < 12; ++i) {
    const int idx = t + 256 * i;        // 3072 uint4 total
    const int kb  = idx >> 10;
    const int o   = (idx >> 2) & 255;
    const int g   = idx & 3;
    const int k8  = kb * 32 + g * 8;
    uint32_t hl[4];
    #pragma unroll
    for (int j = 0; j < 4; ++j) {
      const int ka = k8 + 2 * j, k2 = ka + 1;
      const uint32_t lo = (ka < NROWS) ? (uint32_t)l16[ka][o] : 0u;
      const uint32_t hi = (k2 < NROWS) ? (uint32_t)l16[k2][o] : 0u;
      hl[j] = lo | (hi << 16);
    }
    *(uint4*)(wb + (((size_t)(c * 3 + kb) * 256 + o) * 32 + g * 8)) =
        make_uint4(hl[0], hl[1], hl[2], hl[3]);
  }
}

// ---- Kernel B: MFMA gather, W direct-from-global (no W staging, no W LDS).
//      Grid 256 = 8 btile x 32 cg; 512 threads (8 waves, 2/SIMD). Per wave:
//      o-strip of 32, all 64 b. Per channel: {scatter Y (owner thread clears
//      prev 5 slots + writes 5) | issue 6 af uint4 loads (latency hides
//      under the barrier)} -> barrier -> 12 bf ds_reads + 24 MFMA -> barrier.
//      MFMA roles/C-D map identical to R12 (PASSED): A=W (m16->o),
//      B=Y (m16->b), D: col(lane&15)=b, row=(lane>>4)*4+reg -> o. ----
__global__ __launch_bounds__(512) void kan_gather_kernel(
    const float* __restrict__ x, const unsigned short* __restrict__ wbu,
    const float* __restrict__ t, float* __restrict__ part) {
  __shared__ float  lt[NT];
  __shared__ uint4  YldsRaw[832];               // 64 b x 104 k f16 (13.3 KB)
  __shared__ float4 nA[8][64];
  __shared__ float  sA[8][64];
  __shared__ int    bA[8][64];
  __shared__ float  bounce[64 * 260];           // 66.5 KB epilogue transpose

  unsigned short* Ylds = (unsigned short*)YldsRaw;
  const int tid   = threadIdx.x;
  const int cg    = blockIdx.x & 31;
  const int btile = blockIdx.x >> 5;
  const int wv    = tid >> 6;
  const int lane  = tid & 63;
  const int m16   = lane & 15;
  const int g     = lane >> 4;
  const int ob    = wv * 32;                    // wave's o-base

  if (tid < NT) lt[tid] = t[tid];
  for (int i = tid; i < 832; i += 512)
    YldsRaw[i] = make_uint4(0u, 0u, 0u, 0u);
  __syncthreads();

  // ---- basis: exactly one (c, b) pair per thread ----
  {
    const int c = tid >> 6, bb = tid & 63;
    const float xv = x[(size_t)(btile * 64 + bb) * IN_DIM + cg * 8 + c];
    int i = 3 + (int)floorf((xv + 1.0f) * 32.0f);
    i = i < 3 ? 3 : (i > 66 ? 66 : i);
    while (i > 3 && xv < lt[i]) --i;
    while (i < 66 && xv >= lt[i + 1]) ++i;
    float N0 = 1.f, N1 = 0.f, N2 = 0.f, N3 = 0.f;
    { const float l1 = xv - lt[i], r1 = lt[i + 1] - xv;
      const float tp = N0 / (r1 + l1); N1 = l1 * tp; N0 = r1 * tp; }
    { const float l1 = xv - lt[i], l2 = xv - lt[i - 1];
      const float r1 = lt[i + 1] - xv, r2 = lt[i + 2] - xv;
      float saved = 0.f;
      const float tp0 = N0 / (r1 + l2); const float n0 = saved + r1 * tp0; saved = l2 * tp0;
      const float tp1 = N1 / (r2 + l1); const float n1 = saved + r2 * tp1; saved = l1 * tp1;
      N0 = n0; N1 = n1; N2 = saved; }
    { const float l1 = xv - lt[i], l2 = xv - lt[i - 1], l3 = xv - lt[i - 2];
      const float r1 = lt[i + 1] - xv, r2 = lt[i + 2] - xv, r3 = lt[i + 3] - xv;
      float saved = 0.f;
      const float tp0 = N0 / (r1 + l3); const float n0 = saved + r1 * tp0; saved = l3 * tp0;
      const float tp1 = N1 / (r2 + l2); const float n1 = saved + r2 * tp1; saved = l2 * tp1;
      const float tp2 = N2 / (r3 + l1); const float n2 = saved + r3 * tp2; saved = l1 * tp2;
      N0 = n0; N1 = n1; N2 = n2; N3 = saved; }
    nA[c][bb] = make_float4(N0, N1, N2, N3);
    sA[c][bb] = xv / (1.0f + expf(-xv));
    bA[c][bb] = i - 3;
  }
  __syncthreads();

  const uint4* wbu4 = (const uint4*)wbu;
  f32x4 acc[2][4];
  #pragma unroll
  for (int ot = 0; ot < 2; ++ot)
    #pragma unroll
    for (int bt = 0; bt < 4; ++bt) acc[ot][bt] = f32x4{0.f, 0.f, 0.f, 0.f};

  int prevb = -1;
  for (int ch = 0; ch < 8; ++ch) {
    // scatter Y(ch): row-owner clears previous channel's slots, writes new
    if (tid < 64) {
      unsigned short* yr = Ylds + tid * 104;
      if (prevb >= 0) {
        yr[prevb + 0] = 0; yr[prevb + 1] = 0; yr[prevb + 2] = 0; yr[prevb + 3] = 0;
      }
      const float4 yv = nA[ch][tid];
      const int base = bA[ch][tid];
      yr[base + 0] = __half_as_ushort(__float2half_rn(yv.x));
      yr[base + 1] = __half_as_ushort(__float2half_rn(yv.y));
      yr[base + 2] = __half_as_ushort(__float2half_rn(yv.z));
      yr[base + 3] = __half_as_ushort(__float2half_rn(yv.w));
      yr[67]       = __half_as_ushort(__float2half_rn(sA[ch][tid]));
      prevb = base;
    }
    // issue the 6 A-frag loads now; latency hides under the barrier
    uint4 af[6];
    {
      const int c3 = (cg * 8 + ch) * 3;
      #pragma unroll
      for (int ot = 0; ot < 2; ++ot)
        #pragma unroll
        for (int kb = 0; kb < 3; ++kb)
          af[ot * 3 + kb] =
              wbu4[((size_t)(c3 + kb) * 256 + ob + ot * 16 + m16) * 4 + g];
    }
    __syncthreads();               // Y visible (af also landed)

    #pragma unroll
    for (int kb = 0; kb < 3; ++kb) {
      #pragma unroll
      for (int bt = 0; bt < 4; ++bt) {
        const f16x8 bf = *(const f16x8*)(Ylds + (bt * 16 + m16) * 104 + kb * 32 + g * 8);
        acc[0][bt] = __builtin_amdgcn_mfma_f32_16x16x32_f16(
            __builtin_bit_cast(f16x8, af[0 * 3 + kb]), bf, acc[0][bt], 0, 0, 0);
        acc[1][bt] = __builtin_amdgcn_mfma_f32_16x16x32_f16(
            __builtin_bit_cast(f16x8, af[1 * 3 + kb]), bf, acc[1][bt], 0, 0, 0);
      }
    }
    __syncthreads();               // reads done before next scatter
  }

  // ---- epilogue: acc -> bounce (transpose) -> coalesced partial store ----
  #pragma unroll
  for (int ot = 0; ot < 2; ++ot)
    #pragma unroll
    for (int bt = 0; bt < 4; ++bt)
      #pragma unroll
      for (int r = 0; r < 4; ++r)
        bounce[(bt * 16 + m16) * 260 + ob + ot * 16 + g * 4 + r] = acc[ot][bt][r];
  __syncthreads();
  #pragma unroll
  for (int i = 0; i < 8; ++i) {
    const int idx = tid + 512 * i;   // 4096 float4
    const int b = idx >> 6, o4 = (idx & 63) * 4;
    *(float4*)(part + ((size_t)cg * BATCH + btile * 64 + b) * OUT_DIM + o4) =
        *(const float4*)(bounce + b * 260 + o4);
  }
}

// ---- Kernel C: reduce the 32 c-group partials into out ----
__global__ __launch_bounds__(256) void reduce_kernel(const float* __restrict__ part,
                                                     float* __restrict__ out) {
  const int q = blockIdx.x * 256 + threadIdx.x;   // float4 index, 32768 total
  const int S = BATCH * OUT_DIM / 4;
  const float4* p = (const float4*)part;
  float4 s = p[q];
  #pragma unroll
  for (int k = 1; k < NCG; ++k) {
    const float4 a = p[q + k * S];
    s.x += a.x; s.y += a.y; s.z += a.z; s.w += a.w;
  }
  ((float4*)out)[q] = s;
}

extern "C" void kernel_launch(void* const* d_in, const int* in_sizes, int n_in,
                              void* d_out, int out_size, void* d_ws, size_t ws_size,
                              hipStream_t stream) {
  const float* x = (const float*)d_in[0];
  const float* w = (const float*)d_in[1];
  const float* t = (const float*)d_in[2];
  float* out  = (float*)d_out;
  float* part = (float*)d_ws;                                        // 16 MB
  unsigned short* wb = (unsigned short*)((float*)d_ws + PART_FLOATS); // f16 W
  cvt_kernel<<<IN_DIM, 256, 0, stream>>>(w, wb);
  kan_gather_kernel<<<256, 512, 0, stream>>>(x, wb, t, part);
  reduce_kernel<<<BATCH * OUT_DIM / 4 / 256, 256, 0, stream>>>(part, out);
}